// Round 3
// baseline (515.928 us; speedup 1.0000x reference)
//
#include <hip/hip_runtime.h>

typedef __attribute__((ext_vector_type(8))) short bf16x8;
typedef __attribute__((ext_vector_type(4))) float f32x4;

__device__ __forceinline__ unsigned short f2bf(float f) {
    union { float f; unsigned u; } v; v.f = f;
    unsigned r = (v.u + 0x7FFFu + ((v.u >> 16) & 1u)) >> 16;   // round-to-nearest-even
    return (unsigned short)r;
}
__device__ __forceinline__ unsigned pack2bf(float a, float b) {
    return (unsigned)f2bf(a) | ((unsigned)f2bf(b) << 16);
}
__device__ __forceinline__ float bflo(unsigned u) { union { unsigned u; float f; } v; v.u = u << 16; return v.f; }
__device__ __forceinline__ float bfhi(unsigned u) { union { unsigned u; float f; } v; v.u = u & 0xffff0000u; return v.f; }

// ---------------- setup: zero counters + weight prep (f32 -> bf16 padded [304][320]) ----------------
__global__ void setup_kernel(const float* __restrict__ W1, const float* __restrict__ b1,
                             const float* __restrict__ W2, const float* __restrict__ b2,
                             unsigned short* __restrict__ Wp1, unsigned short* __restrict__ Wp2,
                             float* __restrict__ bp1, float* __restrict__ bp2,
                             int* __restrict__ deg, int* __restrict__ cnt, int* __restrict__ cur, int N) {
    int tid = blockIdx.x * 256 + threadIdx.x;
    if (tid < N) { deg[tid] = 0; cnt[tid] = 0; cur[tid] = 0; }
    if (tid < 304 * 320) {
        int o = tid / 320, k = tid % 320;
        bool in = (o < 300) && (k < 300);
        Wp1[tid] = f2bf(in ? W1[o * 300 + k] : 0.f);
        Wp2[tid] = f2bf(in ? W2[o * 300 + k] : 0.f);
        if (tid < 304) { bp1[tid] = tid < 300 ? b1[tid] : 0.f; bp2[tid] = tid < 300 ? b2[tid] : 0.f; }
    }
}

// ---------------- degree (row/source) + in-degree counts (col/dest) ----------------
__global__ void degcnt_kernel(const int* __restrict__ ei, int E,
                              int* __restrict__ deg, int* __restrict__ cnt) {
    int e = blockIdx.x * 256 + threadIdx.x;
    if (e >= E) return;
    atomicAdd(&deg[ei[e]], 1);        // row
    atomicAdd(&cnt[ei[E + e]], 1);    // col
}

// ---------------- coalesced 3-phase scan: cnt -> indptr ----------------
__global__ void scanA_kernel(const int* __restrict__ cnt, int* __restrict__ bsum, int N) {
    __shared__ int sm[256];
    int i = blockIdx.x * 256 + threadIdx.x;
    sm[threadIdx.x] = (i < N) ? cnt[i] : 0;
    __syncthreads();
    for (int off = 128; off > 0; off >>= 1) {
        if (threadIdx.x < off) sm[threadIdx.x] += sm[threadIdx.x + off];
        __syncthreads();
    }
    if (threadIdx.x == 0) bsum[blockIdx.x] = sm[0];
}

__global__ void scanB_kernel(int* __restrict__ bsum, int nb, int* __restrict__ indptr, int N) {
    __shared__ int sm[256];
    int t = threadIdx.x;
    int v = (t < nb) ? bsum[t] : 0;
    sm[t] = v; __syncthreads();
    for (int off = 1; off < 256; off <<= 1) {
        int u = (t >= off) ? sm[t - off] : 0;
        __syncthreads();
        sm[t] += u;
        __syncthreads();
    }
    if (t < nb) bsum[t] = sm[t] - v;          // exclusive block offsets
    if (t == 255) indptr[N] = sm[255];        // total = E
}

__global__ void scanC_kernel(const int* __restrict__ cnt, const int* __restrict__ bsum,
                             int* __restrict__ indptr, const int* __restrict__ deg,
                             float* __restrict__ dis, int N) {
    __shared__ int sm[256];
    int i = blockIdx.x * 256 + threadIdx.x;
    int c = (i < N) ? cnt[i] : 0;
    sm[threadIdx.x] = c; __syncthreads();
    for (int off = 1; off < 256; off <<= 1) {
        int u = (threadIdx.x >= off) ? sm[threadIdx.x - off] : 0;
        __syncthreads();
        sm[threadIdx.x] += u;
        __syncthreads();
    }
    if (i < N) {
        indptr[i] = bsum[blockIdx.x] + sm[threadIdx.x] - c;   // exclusive prefix
        dis[i] = 1.0f / sqrtf((float)(deg[i] + 1));           // +1 self-loop
    }
}

// ---------------- CSR fill: csr[indptr[col]+slot] = row ----------------
__global__ void fill_kernel(const int* __restrict__ ei, int E,
                            const int* __restrict__ indptr, int* __restrict__ cur,
                            int* __restrict__ csr) {
    int e = blockIdx.x * 256 + threadIdx.x;
    if (e >= E) return;
    int r = ei[e], c = ei[E + e];
    int pos = indptr[c] + atomicAdd(&cur[c], 1);
    csr[pos] = r;
}

// ---------------- A-fragment straight from x: mean over T=4, bf16 pack ----------------
__device__ __forceinline__ bf16x8 make_frag_x(const float* __restrict__ xp, bool valid, int k0) {
    float v[8] = {0.f,0.f,0.f,0.f,0.f,0.f,0.f,0.f};
    if (valid && k0 < 300) {
        bool full = (k0 + 8) <= 300;   // k0 multiple of 8: full for k0<=288; k0==296 -> half
        #pragma unroll
        for (int t = 0; t < 4; ++t) {
            const float* q = xp + t * 300 + k0;
            float4 lo = *(const float4*)q;
            v[0] += lo.x; v[1] += lo.y; v[2] += lo.z; v[3] += lo.w;
            if (full) {
                float4 hi = *(const float4*)(q + 4);
                v[4] += hi.x; v[5] += hi.y; v[6] += hi.z; v[7] += hi.w;
            }
        }
    }
    union { unsigned short u[8]; bf16x8 vec; } p;
    #pragma unroll
    for (int j = 0; j < 8; ++j) p.u[j] = f2bf(v[j] * 0.25f);
    return p.vec;
}

// ---------------- GEMM1 (pool fused): g[n][o] = bf16(dis[n]*(mean_t(x)@W1^T + b1)) ----------------
// out: bf16 padded [Mpad][320] (cols>=304 and pad rows unwritten -> never read downstream)
__global__ __launch_bounds__(256) void gemm_x_kernel(
    const float* __restrict__ x, const unsigned short* __restrict__ Wp,
    const float* __restrict__ bp, const float* __restrict__ dis,
    unsigned short* __restrict__ g, int N)
{
    const int lane = threadIdx.x & 63;
    const int wave = threadIdx.x >> 6;
    const int l15 = lane & 15, lhi = lane >> 4;
    const int rowBase = blockIdx.x * 128 + wave * 32;

    f32x4 acc0[19], acc1[19];
    #pragma unroll
    for (int i = 0; i < 19; ++i) { acc0[i] = (f32x4){0.f,0.f,0.f,0.f}; acc1[i] = (f32x4){0.f,0.f,0.f,0.f}; }

    const int r0 = rowBase + l15, r1 = r0 + 16;
    const float* xp0 = x + (size_t)r0 * 1200;
    const float* xp1 = x + (size_t)r1 * 1200;
    const unsigned short* Wl = Wp + (size_t)l15 * 320 + lhi * 8;

    for (int ks = 0; ks < 10; ++ks) {
        int k0 = lhi * 8 + ks * 32;
        bf16x8 a0 = make_frag_x(xp0, r0 < N, k0);
        bf16x8 a1 = make_frag_x(xp1, r1 < N, k0);
        #pragma unroll
        for (int cf = 0; cf < 19; ++cf) {
            bf16x8 b = *(const bf16x8*)(Wl + cf * 16 * 320 + ks * 32);
            acc0[cf] = __builtin_amdgcn_mfma_f32_16x16x32_bf16(a0, b, acc0[cf], 0, 0, 0);
            acc1[cf] = __builtin_amdgcn_mfma_f32_16x16x32_bf16(a1, b, acc1[cf], 0, 0, 0);
        }
    }

    const int n0 = rowBase + lhi * 4;
    float d0[4], d1[4];
    #pragma unroll
    for (int r = 0; r < 4; ++r) {
        d0[r] = (n0 + r      < N) ? dis[n0 + r]      : 0.f;
        d1[r] = (n0 + 16 + r < N) ? dis[n0 + 16 + r] : 0.f;
    }
    #pragma unroll
    for (int cf = 0; cf < 19; ++cf) {
        int o = cf * 16 + l15;
        if (o < 300) {
            float bo = bp[o];
            #pragma unroll
            for (int r = 0; r < 4; ++r) {
                if (n0 + r < N)      g[(size_t)(n0 + r) * 320 + o]      = f2bf(d0[r] * (acc0[cf][r] + bo));
                if (n0 + 16 + r < N) g[(size_t)(n0 + 16 + r) * 320 + o] = f2bf(d1[r] * (acc1[cf][r] + bo));
            }
        }
    }
}

// ---------------- GEMM2: A = bf16 padded [Mpad][320] (hb), out bf16 padded ----------------
__global__ __launch_bounds__(256) void gemm_h_kernel(
    const unsigned short* __restrict__ A, const unsigned short* __restrict__ Wp,
    const float* __restrict__ bp, const float* __restrict__ dis,
    unsigned short* __restrict__ g, int N)
{
    const int lane = threadIdx.x & 63;
    const int wave = threadIdx.x >> 6;
    const int l15 = lane & 15, lhi = lane >> 4;
    const int rowBase = blockIdx.x * 128 + wave * 32;

    f32x4 acc0[19], acc1[19];
    #pragma unroll
    for (int i = 0; i < 19; ++i) { acc0[i] = (f32x4){0.f,0.f,0.f,0.f}; acc1[i] = (f32x4){0.f,0.f,0.f,0.f}; }

    const unsigned short* Ap0 = A + (size_t)(rowBase + l15) * 320 + lhi * 8;
    const unsigned short* Ap1 = Ap0 + 16 * 320;
    const unsigned short* Wl  = Wp + (size_t)l15 * 320 + lhi * 8;

    for (int ks = 0; ks < 10; ++ks) {
        bf16x8 a0 = *(const bf16x8*)(Ap0 + ks * 32);
        bf16x8 a1 = *(const bf16x8*)(Ap1 + ks * 32);
        #pragma unroll
        for (int cf = 0; cf < 19; ++cf) {
            bf16x8 b = *(const bf16x8*)(Wl + cf * 16 * 320 + ks * 32);
            acc0[cf] = __builtin_amdgcn_mfma_f32_16x16x32_bf16(a0, b, acc0[cf], 0, 0, 0);
            acc1[cf] = __builtin_amdgcn_mfma_f32_16x16x32_bf16(a1, b, acc1[cf], 0, 0, 0);
        }
    }

    const int n0 = rowBase + lhi * 4;
    float d0[4], d1[4];
    #pragma unroll
    for (int r = 0; r < 4; ++r) {
        d0[r] = (n0 + r      < N) ? dis[n0 + r]      : 0.f;
        d1[r] = (n0 + 16 + r < N) ? dis[n0 + 16 + r] : 0.f;
    }
    #pragma unroll
    for (int cf = 0; cf < 19; ++cf) {
        int o = cf * 16 + l15;
        if (o < 300) {
            float bo = bp[o];
            #pragma unroll
            for (int r = 0; r < 4; ++r) {
                if (n0 + r < N)      g[(size_t)(n0 + r) * 320 + o]      = f2bf(d0[r] * (acc0[cf][r] + bo));
                if (n0 + 16 + r < N) g[(size_t)(n0 + 16 + r) * 320 + o] = f2bf(d1[r] * (acc1[cf][r] + bo));
            }
        }
    }
}

// ---------------- propagate (bf16 g, pre-scaled by dis): out[i] = dis[i]*(g[i]+sum g[src]) ----------------
// MODE 0: f32 compact [N][300] to d_out. MODE 1: leaky_relu + bf16 padded [Mpad][320].
template<int MODE>
__global__ void prop_kernel(const unsigned short* __restrict__ g, const int* __restrict__ indptr,
                            const int* __restrict__ csr, const float* __restrict__ dis,
                            void* __restrict__ outp, int N, int Mpad) {
    int wave = threadIdx.x >> 6;
    int lane = threadIdx.x & 63;
    int n = blockIdx.x * 4 + wave;
    if (n >= (MODE ? Mpad : N)) return;
    float aL[3] = {0.f,0.f,0.f}, aH[3] = {0.f,0.f,0.f};
    if (n < N) {
        const unsigned* gn = (const unsigned*)(g + (size_t)n * 320);
        #pragma unroll
        for (int s = 0; s < 3; ++s) {
            int e = lane + 64 * s;                 // uint index; bf16 pair (2e, 2e+1)
            if (e < 150) { unsigned u = gn[e]; aL[s] = bflo(u); aH[s] = bfhi(u); }
        }
        int beg = indptr[n], end = indptr[n + 1];
        for (int j = beg; j < end; ++j) {
            int src = csr[j];
            const unsigned* gs = (const unsigned*)(g + (size_t)src * 320);
            #pragma unroll
            for (int s = 0; s < 3; ++s) {
                int e = lane + 64 * s;
                if (e < 150) { unsigned u = gs[e]; aL[s] += bflo(u); aH[s] += bfhi(u); }
            }
        }
        float dn = dis[n];
        #pragma unroll
        for (int s = 0; s < 3; ++s) { aL[s] *= dn; aH[s] *= dn; }
    }
    if (MODE == 0) {
        float* out = (float*)outp + (size_t)n * 300;
        #pragma unroll
        for (int s = 0; s < 3; ++s) {
            int e = lane + 64 * s;
            if (e < 150) { float2 st = {aL[s], aH[s]}; *(float2*)(out + 2 * e) = st; }
        }
    } else {
        unsigned* h = (unsigned*)outp + (size_t)n * 160;
        #pragma unroll
        for (int s = 0; s < 3; ++s) {
            int e = lane + 64 * s;
            if (e < 150) {
                float vL = aL[s]; vL = vL > 0.f ? vL : 0.01f * vL;
                float vH = aH[s]; vH = vH > 0.f ? vH : 0.01f * vH;
                h[e] = pack2bf(vL, vH);
            } else if (e < 160) {
                h[e] = 0;                          // K-pad cols 300..319
            }
        }
    }
}

extern "C" void kernel_launch(void* const* d_in, const int* in_sizes, int n_in,
                              void* d_out, int out_size, void* d_ws, size_t ws_size,
                              hipStream_t stream) {
    const float* x  = (const float*)d_in[0];
    const int*   ei = (const int*)d_in[1];
    const float* W1 = (const float*)d_in[2];
    const float* b1 = (const float*)d_in[3];
    const float* W2 = (const float*)d_in[4];
    const float* b2 = (const float*)d_in[5];
    float* out = (float*)d_out;

    const int N = in_sizes[0] / 1200;     // 50000
    const int E = in_sizes[1] / 2;        // 250000
    const int Mpad = ((N + 127) / 128) * 128;   // 50048
    const int NB = (N + 255) / 256;       // 196 scan tiles

    // ---- carve workspace (256B aligned) ----
    char* p = (char*)d_ws;
    auto carve = [&](size_t bytes) -> char* {
        char* r = p; p += (bytes + 255) & ~(size_t)255; return r;
    };
    unsigned short* g1   = (unsigned short*)carve((size_t)Mpad * 320 * 2);  // 32 MB
    unsigned short* hb   = (unsigned short*)carve((size_t)Mpad * 320 * 2);  // 32 MB
    unsigned short* g2   = (unsigned short*)carve((size_t)Mpad * 320 * 2);  // 32 MB
    float* dis           = (float*)carve((size_t)N * 4);
    int* deg             = (int*)carve((size_t)N * 4);
    int* cnt             = (int*)carve((size_t)N * 4);
    int* indptr          = (int*)carve((size_t)(N + 1) * 4);
    int* cur             = (int*)carve((size_t)N * 4);
    int* csr             = (int*)carve((size_t)E * 4);
    int* bsum            = (int*)carve(256 * 4);
    unsigned short* Wp1  = (unsigned short*)carve(304 * 320 * 2);
    unsigned short* Wp2  = (unsigned short*)carve(304 * 320 * 2);
    float* bp1           = (float*)carve(304 * 4);
    float* bp2           = (float*)carve(304 * 4);

    setup_kernel <<<(304 * 320 + 255) / 256, 256, 0, stream>>>(W1, b1, W2, b2, Wp1, Wp2, bp1, bp2,
                                                               deg, cnt, cur, N);
    degcnt_kernel<<<(E + 255) / 256, 256, 0, stream>>>(ei, E, deg, cnt);
    scanA_kernel <<<NB, 256, 0, stream>>>(cnt, bsum, N);
    scanB_kernel <<<1, 256, 0, stream>>>(bsum, NB, indptr, N);
    scanC_kernel <<<NB, 256, 0, stream>>>(cnt, bsum, indptr, deg, dis, N);
    fill_kernel  <<<(E + 255) / 256, 256, 0, stream>>>(ei, E, indptr, cur, csr);

    // layer 1: g1 = bf16(dis*(mean_t(x)@W1^T + b1)) fused pool; prop+leaky -> hb (bf16 padded)
    gemm_x_kernel<<<Mpad / 128, 256, 0, stream>>>(x, Wp1, bp1, dis, g1, N);
    prop_kernel<1><<<Mpad / 4, 256, 0, stream>>>(g1, indptr, csr, dis, hb, N, Mpad);
    // layer 2: g2 = bf16(dis*(hb@W2^T + b2)); final prop -> d_out (f32)
    gemm_h_kernel<<<Mpad / 128, 256, 0, stream>>>(hb, Wp2, bp2, dis, g2, N);
    prop_kernel<0><<<(N + 3) / 4, 256, 0, stream>>>(g2, indptr, csr, dis, out, N, Mpad);
}

// Round 4
// 450.522 us; speedup vs baseline: 1.1452x; 1.1452x over previous
//
#include <hip/hip_runtime.h>

typedef __attribute__((ext_vector_type(8))) short bf16x8;
typedef __attribute__((ext_vector_type(4))) float f32x4;

__device__ __forceinline__ unsigned short f2bf(float f) {
    union { float f; unsigned u; } v; v.f = f;
    unsigned r = (v.u + 0x7FFFu + ((v.u >> 16) & 1u)) >> 16;   // round-to-nearest-even
    return (unsigned short)r;
}
__device__ __forceinline__ unsigned pack2bf(float a, float b) {
    return (unsigned)f2bf(a) | ((unsigned)f2bf(b) << 16);
}
__device__ __forceinline__ float bflo(unsigned u) { union { unsigned u; float f; } v; v.u = u << 16; return v.f; }
__device__ __forceinline__ float bfhi(unsigned u) { union { unsigned u; float f; } v; v.u = u & 0xffff0000u; return v.f; }

// ---------------- K0: mean-pool over T=4 + bf16 cast, padded [Mpad][320] ----------------
__global__ void pool_kernel(const float* __restrict__ x, unsigned short* __restrict__ xm,
                            int N, int Mpad) {
    int tid = blockIdx.x * 256 + threadIdx.x;
    if (tid >= Mpad * 40) return;
    int n = tid / 40, k8 = tid % 40;
    int k = k8 * 8;
    float v[8] = {0.f,0.f,0.f,0.f,0.f,0.f,0.f,0.f};
    if (n < N && k < 300) {
        const float* xp = x + (size_t)n * 1200 + k;
        #pragma unroll
        for (int t = 0; t < 4; ++t) {
            const float4 lo = *(const float4*)(xp + t * 300);
            v[0] += lo.x; v[1] += lo.y; v[2] += lo.z; v[3] += lo.w;
            if (k + 4 < 300) {   // k==296 tail: cols 300..303 stay zero
                const float4 hi = *(const float4*)(xp + t * 300 + 4);
                v[4] += hi.x; v[5] += hi.y; v[6] += hi.z; v[7] += hi.w;
            }
        }
    }
    union { unsigned short u[8]; bf16x8 vec; } p;
    #pragma unroll
    for (int j = 0; j < 8; ++j) p.u[j] = f2bf(v[j] * 0.25f);
    *(bf16x8*)(xm + (size_t)tid * 8) = p.vec;   // tid*8 == n*320 + k
}

// ---------------- setup: zero counters + weight prep (f32 -> bf16 padded [304][320]) ----------------
__global__ void setup_kernel(const float* __restrict__ W1, const float* __restrict__ b1,
                             const float* __restrict__ W2, const float* __restrict__ b2,
                             unsigned short* __restrict__ Wp1, unsigned short* __restrict__ Wp2,
                             float* __restrict__ bp1, float* __restrict__ bp2,
                             int* __restrict__ deg, int* __restrict__ cnt, int* __restrict__ cur, int N) {
    int tid = blockIdx.x * 256 + threadIdx.x;
    if (tid < N) { deg[tid] = 0; cnt[tid] = 0; cur[tid] = 0; }
    if (tid < 304 * 320) {
        int o = tid / 320, k = tid % 320;
        bool in = (o < 300) && (k < 300);
        Wp1[tid] = f2bf(in ? W1[o * 300 + k] : 0.f);
        Wp2[tid] = f2bf(in ? W2[o * 300 + k] : 0.f);
        if (tid < 304) { bp1[tid] = tid < 300 ? b1[tid] : 0.f; bp2[tid] = tid < 300 ? b2[tid] : 0.f; }
    }
}

// ---------------- degree (row/source) + in-degree counts (col/dest) ----------------
__global__ void degcnt_kernel(const int* __restrict__ ei, int E,
                              int* __restrict__ deg, int* __restrict__ cnt) {
    int e = blockIdx.x * 256 + threadIdx.x;
    if (e >= E) return;
    atomicAdd(&deg[ei[e]], 1);        // row
    atomicAdd(&cnt[ei[E + e]], 1);    // col
}

// ---------------- coalesced 3-phase scan: cnt -> indptr ----------------
__global__ void scanA_kernel(const int* __restrict__ cnt, int* __restrict__ bsum, int N) {
    __shared__ int sm[256];
    int i = blockIdx.x * 256 + threadIdx.x;
    sm[threadIdx.x] = (i < N) ? cnt[i] : 0;
    __syncthreads();
    for (int off = 128; off > 0; off >>= 1) {
        if (threadIdx.x < off) sm[threadIdx.x] += sm[threadIdx.x + off];
        __syncthreads();
    }
    if (threadIdx.x == 0) bsum[blockIdx.x] = sm[0];
}

__global__ void scanB_kernel(int* __restrict__ bsum, int nb, int* __restrict__ indptr, int N) {
    __shared__ int sm[256];
    int t = threadIdx.x;
    int v = (t < nb) ? bsum[t] : 0;
    sm[t] = v; __syncthreads();
    for (int off = 1; off < 256; off <<= 1) {
        int u = (t >= off) ? sm[t - off] : 0;
        __syncthreads();
        sm[t] += u;
        __syncthreads();
    }
    if (t < nb) bsum[t] = sm[t] - v;          // exclusive block offsets
    if (t == 255) indptr[N] = sm[255];        // total = E
}

__global__ void scanC_kernel(const int* __restrict__ cnt, const int* __restrict__ bsum,
                             int* __restrict__ indptr, const int* __restrict__ deg,
                             float* __restrict__ dis, int N) {
    __shared__ int sm[256];
    int i = blockIdx.x * 256 + threadIdx.x;
    int c = (i < N) ? cnt[i] : 0;
    sm[threadIdx.x] = c; __syncthreads();
    for (int off = 1; off < 256; off <<= 1) {
        int u = (threadIdx.x >= off) ? sm[threadIdx.x - off] : 0;
        __syncthreads();
        sm[threadIdx.x] += u;
        __syncthreads();
    }
    if (i < N) {
        indptr[i] = bsum[blockIdx.x] + sm[threadIdx.x] - c;   // exclusive prefix
        dis[i] = 1.0f / sqrtf((float)(deg[i] + 1));           // +1 self-loop
    }
}

// ---------------- CSR fill: csr[indptr[col]+slot] = row ----------------
__global__ void fill_kernel(const int* __restrict__ ei, int E,
                            const int* __restrict__ indptr, int* __restrict__ cur,
                            int* __restrict__ csr) {
    int e = blockIdx.x * 256 + threadIdx.x;
    if (e >= E) return;
    int r = ei[e], c = ei[E + e];
    int pos = indptr[c] + atomicAdd(&cur[c], 1);
    csr[pos] = r;
}

// ---------------- GEMM: g[n][o] = bf16(dis[n]*(sum_k A[n][k]*Wp[o][k] + bp[o])) ----------------
// Wave tile = 16 rows x 304 cols: acc = 19 f32x4 = 76 VGPR (headroom for B-load pipelining,
// round-3's 152-VGPR acc left none -> serialized loads). BM=64, grid 782 blocks (~12 waves/CU).
__global__ __launch_bounds__(256) void gemm_kernel(
    const unsigned short* __restrict__ A, const unsigned short* __restrict__ Wp,
    const float* __restrict__ bp, const float* __restrict__ dis,
    unsigned short* __restrict__ g, int N)
{
    const int lane = threadIdx.x & 63;
    const int wave = threadIdx.x >> 6;
    const int l15 = lane & 15, lhi = lane >> 4;
    const int rowBase = blockIdx.x * 64 + wave * 16;

    f32x4 acc[19];
    #pragma unroll
    for (int i = 0; i < 19; ++i) acc[i] = (f32x4){0.f,0.f,0.f,0.f};

    const unsigned short* Ap = A + (size_t)(rowBase + l15) * 320 + lhi * 8;
    const unsigned short* Wl = Wp + (size_t)l15 * 320 + lhi * 8;

    for (int ks = 0; ks < 10; ++ks) {
        bf16x8 a = *(const bf16x8*)(Ap + ks * 32);
        #pragma unroll
        for (int cf = 0; cf < 19; ++cf) {
            bf16x8 b = *(const bf16x8*)(Wl + cf * 16 * 320 + ks * 32);
            acc[cf] = __builtin_amdgcn_mfma_f32_16x16x32_bf16(a, b, acc[cf], 0, 0, 0);
        }
    }

    const int n0 = rowBase + lhi * 4;
    float d[4];
    #pragma unroll
    for (int r = 0; r < 4; ++r) d[r] = (n0 + r < N) ? dis[n0 + r] : 0.f;
    #pragma unroll
    for (int cf = 0; cf < 19; ++cf) {
        int o = cf * 16 + l15;
        if (o < 300) {
            float bo = bp[o];
            #pragma unroll
            for (int r = 0; r < 4; ++r)
                if (n0 + r < N) g[(size_t)(n0 + r) * 320 + o] = f2bf(d[r] * (acc[cf][r] + bo));
        }
    }
}

// ---------------- propagate (bf16 g, pre-scaled by dis): out[i] = dis[i]*(g[i]+sum g[src]) ----------------
// Neighbor loop unrolled x4 with independent accumulator sets: the L3 gather latency
// (~500cyc) was serialized behind each acc add; 4 independent chains expose MLP.
// MODE 0: f32 compact [N][300] to d_out. MODE 1: leaky_relu + bf16 padded [Mpad][320].
template<int MODE>
__global__ void prop_kernel(const unsigned short* __restrict__ g, const int* __restrict__ indptr,
                            const int* __restrict__ csr, const float* __restrict__ dis,
                            void* __restrict__ outp, int N, int Mpad) {
    int wave = threadIdx.x >> 6;
    int lane = threadIdx.x & 63;
    int n = blockIdx.x * 4 + wave;
    if (n >= (MODE ? Mpad : N)) return;
    float aL0[3] = {0.f,0.f,0.f}, aH0[3] = {0.f,0.f,0.f};
    float aL1[3] = {0.f,0.f,0.f}, aH1[3] = {0.f,0.f,0.f};
    float aL2[3] = {0.f,0.f,0.f}, aH2[3] = {0.f,0.f,0.f};
    float aL3[3] = {0.f,0.f,0.f}, aH3[3] = {0.f,0.f,0.f};
    if (n < N) {
        const unsigned* gn = (const unsigned*)(g + (size_t)n * 320);
        #pragma unroll
        for (int s = 0; s < 3; ++s) {
            int e = lane + 64 * s;                 // uint index; bf16 pair (2e, 2e+1)
            if (e < 150) { unsigned u = gn[e]; aL0[s] = bflo(u); aH0[s] = bfhi(u); }
        }
        int beg = indptr[n], end = indptr[n + 1];
        int j = beg;
        for (; j + 4 <= end; j += 4) {
            int s0 = csr[j], s1 = csr[j+1], s2 = csr[j+2], s3 = csr[j+3];
            const unsigned* g0 = (const unsigned*)(g + (size_t)s0 * 320);
            const unsigned* g1 = (const unsigned*)(g + (size_t)s1 * 320);
            const unsigned* g2 = (const unsigned*)(g + (size_t)s2 * 320);
            const unsigned* g3 = (const unsigned*)(g + (size_t)s3 * 320);
            #pragma unroll
            for (int s = 0; s < 3; ++s) {
                int e = lane + 64 * s;
                if (e < 150) {
                    unsigned u0 = g0[e], u1 = g1[e], u2 = g2[e], u3 = g3[e];
                    aL0[s] += bflo(u0); aH0[s] += bfhi(u0);
                    aL1[s] += bflo(u1); aH1[s] += bfhi(u1);
                    aL2[s] += bflo(u2); aH2[s] += bfhi(u2);
                    aL3[s] += bflo(u3); aH3[s] += bfhi(u3);
                }
            }
        }
        for (; j < end; ++j) {
            int src = csr[j];
            const unsigned* gs = (const unsigned*)(g + (size_t)src * 320);
            #pragma unroll
            for (int s = 0; s < 3; ++s) {
                int e = lane + 64 * s;
                if (e < 150) { unsigned u = gs[e]; aL0[s] += bflo(u); aH0[s] += bfhi(u); }
            }
        }
        float dn = dis[n];
        #pragma unroll
        for (int s = 0; s < 3; ++s) {
            aL0[s] = dn * ((aL0[s] + aL1[s]) + (aL2[s] + aL3[s]));
            aH0[s] = dn * ((aH0[s] + aH1[s]) + (aH2[s] + aH3[s]));
        }
    }
    if (MODE == 0) {
        float* out = (float*)outp + (size_t)n * 300;
        #pragma unroll
        for (int s = 0; s < 3; ++s) {
            int e = lane + 64 * s;
            if (e < 150) { float2 st = {aL0[s], aH0[s]}; *(float2*)(out + 2 * e) = st; }
        }
    } else {
        unsigned* h = (unsigned*)outp + (size_t)n * 160;
        #pragma unroll
        for (int s = 0; s < 3; ++s) {
            int e = lane + 64 * s;
            if (e < 150) {
                float vL = aL0[s]; vL = vL > 0.f ? vL : 0.01f * vL;
                float vH = aH0[s]; vH = vH > 0.f ? vH : 0.01f * vH;
                h[e] = pack2bf(vL, vH);
            } else if (e < 160) {
                h[e] = 0;                          // K-pad cols 300..319
            }
        }
    }
}

extern "C" void kernel_launch(void* const* d_in, const int* in_sizes, int n_in,
                              void* d_out, int out_size, void* d_ws, size_t ws_size,
                              hipStream_t stream) {
    const float* x  = (const float*)d_in[0];
    const int*   ei = (const int*)d_in[1];
    const float* W1 = (const float*)d_in[2];
    const float* b1 = (const float*)d_in[3];
    const float* W2 = (const float*)d_in[4];
    const float* b2 = (const float*)d_in[5];
    float* out = (float*)d_out;

    const int N = in_sizes[0] / 1200;     // 50000
    const int E = in_sizes[1] / 2;        // 250000
    const int Mpad = ((N + 127) / 128) * 128;   // 50048
    const int NB = (N + 255) / 256;       // 196 scan tiles

    // ---- carve workspace (256B aligned) ----
    char* p = (char*)d_ws;
    auto carve = [&](size_t bytes) -> char* {
        char* r = p; p += (bytes + 255) & ~(size_t)255; return r;
    };
    unsigned short* xm   = (unsigned short*)carve((size_t)Mpad * 320 * 2);  // 32 MB
    unsigned short* g1   = (unsigned short*)carve((size_t)Mpad * 320 * 2);  // 32 MB
    unsigned short* hb   = (unsigned short*)carve((size_t)Mpad * 320 * 2);  // 32 MB
    unsigned short* g2   = (unsigned short*)carve((size_t)Mpad * 320 * 2);  // 32 MB
    float* dis           = (float*)carve((size_t)N * 4);
    int* deg             = (int*)carve((size_t)N * 4);
    int* cnt             = (int*)carve((size_t)N * 4);
    int* indptr          = (int*)carve((size_t)(N + 1) * 4);
    int* cur             = (int*)carve((size_t)N * 4);
    int* csr             = (int*)carve((size_t)E * 4);
    int* bsum            = (int*)carve(256 * 4);
    unsigned short* Wp1  = (unsigned short*)carve(304 * 320 * 2);
    unsigned short* Wp2  = (unsigned short*)carve(304 * 320 * 2);
    float* bp1           = (float*)carve(304 * 4);
    float* bp2           = (float*)carve(304 * 4);

    setup_kernel <<<(304 * 320 + 255) / 256, 256, 0, stream>>>(W1, b1, W2, b2, Wp1, Wp2, bp1, bp2,
                                                               deg, cnt, cur, N);
    pool_kernel  <<<(Mpad * 40 + 255) / 256, 256, 0, stream>>>(x, xm, N, Mpad);
    degcnt_kernel<<<(E + 255) / 256, 256, 0, stream>>>(ei, E, deg, cnt);
    scanA_kernel <<<NB, 256, 0, stream>>>(cnt, bsum, N);
    scanB_kernel <<<1, 256, 0, stream>>>(bsum, NB, indptr, N);
    scanC_kernel <<<NB, 256, 0, stream>>>(cnt, bsum, indptr, deg, dis, N);
    fill_kernel  <<<(E + 255) / 256, 256, 0, stream>>>(ei, E, indptr, cur, csr);

    // layer 1: g1 = bf16(dis*(xm@W1^T + b1)); prop+leaky -> hb (bf16 padded)
    gemm_kernel  <<<Mpad / 64, 256, 0, stream>>>(xm, Wp1, bp1, dis, g1, N);
    prop_kernel<1><<<Mpad / 4, 256, 0, stream>>>(g1, indptr, csr, dis, hb, N, Mpad);
    // layer 2: g2 = bf16(dis*(hb@W2^T + b2)); final prop -> d_out (f32)
    gemm_kernel  <<<Mpad / 64, 256, 0, stream>>>(hb, Wp2, bp2, dis, g2, N);
    prop_kernel<0><<<(N + 3) / 4, 256, 0, stream>>>(g2, indptr, csr, dis, out, N, Mpad);
}

// Round 5
// 358.215 us; speedup vs baseline: 1.4403x; 1.2577x over previous
//
#include <hip/hip_runtime.h>

typedef __attribute__((ext_vector_type(8))) short bf16x8;
typedef __attribute__((ext_vector_type(4))) float f32x4;

__device__ __forceinline__ unsigned short f2bf(float f) {
    union { float f; unsigned u; } v; v.f = f;
    unsigned r = (v.u + 0x7FFFu + ((v.u >> 16) & 1u)) >> 16;   // round-to-nearest-even
    return (unsigned short)r;
}
__device__ __forceinline__ unsigned pack2bf(float a, float b) {
    return (unsigned)f2bf(a) | ((unsigned)f2bf(b) << 16);
}
__device__ __forceinline__ float bflo(unsigned u) { union { unsigned u; float f; } v; v.u = u << 16; return v.f; }
__device__ __forceinline__ float bfhi(unsigned u) { union { unsigned u; float f; } v; v.u = u & 0xffff0000u; return v.f; }

// ---------------- K0: mean-pool over T=4 + bf16 cast, padded [Mpad][320] ----------------
__global__ void pool_kernel(const float* __restrict__ x, unsigned short* __restrict__ xm,
                            int N, int Mpad) {
    int tid = blockIdx.x * 256 + threadIdx.x;
    if (tid >= Mpad * 40) return;
    int n = tid / 40, k8 = tid % 40;
    int k = k8 * 8;
    float v[8] = {0.f,0.f,0.f,0.f,0.f,0.f,0.f,0.f};
    if (n < N && k < 300) {
        const float* xp = x + (size_t)n * 1200 + k;
        #pragma unroll
        for (int t = 0; t < 4; ++t) {
            const float4 lo = *(const float4*)(xp + t * 300);
            v[0] += lo.x; v[1] += lo.y; v[2] += lo.z; v[3] += lo.w;
            if (k + 4 < 300) {   // k==296 tail: cols 300..303 stay zero
                const float4 hi = *(const float4*)(xp + t * 300 + 4);
                v[4] += hi.x; v[5] += hi.y; v[6] += hi.z; v[7] += hi.w;
            }
        }
    }
    union { unsigned short u[8]; bf16x8 vec; } p;
    #pragma unroll
    for (int j = 0; j < 8; ++j) p.u[j] = f2bf(v[j] * 0.25f);
    *(bf16x8*)(xm + (size_t)tid * 8) = p.vec;   // tid*8 == n*320 + k
}

// ---------------- setup: zero counters + weight prep ----------------
// W [300][300] f32 -> staged bf16 layout Ws[ks][col][kk]: ks=k/32 (10 steps), col<304, kk=k%32.
// Each K-step panel is a contiguous 19456B chunk, so GEMM staging is a linear 16B-chunk copy.
__global__ void setup_kernel(const float* __restrict__ W1, const float* __restrict__ b1,
                             const float* __restrict__ W2, const float* __restrict__ b2,
                             unsigned short* __restrict__ Ws1, unsigned short* __restrict__ Ws2,
                             float* __restrict__ bp1, float* __restrict__ bp2,
                             int* __restrict__ deg, int* __restrict__ cnt, int* __restrict__ cur, int N) {
    int tid = blockIdx.x * 256 + threadIdx.x;
    if (tid < N) { deg[tid] = 0; cnt[tid] = 0; cur[tid] = 0; }
    if (tid < 304 * 320) {
        int c = tid / 320, k = tid % 320;
        int ks = k / 32, kk = k % 32;
        int dst = ks * 9728 + c * 32 + kk;       // 9728 = 304*32 ushorts per K-step
        bool in = (c < 300) && (k < 300);
        Ws1[dst] = f2bf(in ? W1[c * 300 + k] : 0.f);
        Ws2[dst] = f2bf(in ? W2[c * 300 + k] : 0.f);
        if (tid < 304) { bp1[tid] = tid < 300 ? b1[tid] : 0.f; bp2[tid] = tid < 300 ? b2[tid] : 0.f; }
    }
}

// ---------------- degree (row/source) + in-degree counts (col/dest) ----------------
__global__ void degcnt_kernel(const int* __restrict__ ei, int E,
                              int* __restrict__ deg, int* __restrict__ cnt) {
    int e = blockIdx.x * 256 + threadIdx.x;
    if (e >= E) return;
    atomicAdd(&deg[ei[e]], 1);        // row
    atomicAdd(&cnt[ei[E + e]], 1);    // col
}

// ---------------- coalesced 3-phase scan: cnt -> indptr ----------------
__global__ void scanA_kernel(const int* __restrict__ cnt, int* __restrict__ bsum, int N) {
    __shared__ int sm[256];
    int i = blockIdx.x * 256 + threadIdx.x;
    sm[threadIdx.x] = (i < N) ? cnt[i] : 0;
    __syncthreads();
    for (int off = 128; off > 0; off >>= 1) {
        if (threadIdx.x < off) sm[threadIdx.x] += sm[threadIdx.x + off];
        __syncthreads();
    }
    if (threadIdx.x == 0) bsum[blockIdx.x] = sm[0];
}

__global__ void scanB_kernel(int* __restrict__ bsum, int nb, int* __restrict__ indptr, int N) {
    __shared__ int sm[256];
    int t = threadIdx.x;
    int v = (t < nb) ? bsum[t] : 0;
    sm[t] = v; __syncthreads();
    for (int off = 1; off < 256; off <<= 1) {
        int u = (t >= off) ? sm[t - off] : 0;
        __syncthreads();
        sm[t] += u;
        __syncthreads();
    }
    if (t < nb) bsum[t] = sm[t] - v;          // exclusive block offsets
    if (t == 255) indptr[N] = sm[255];        // total = E
}

__global__ void scanC_kernel(const int* __restrict__ cnt, const int* __restrict__ bsum,
                             int* __restrict__ indptr, const int* __restrict__ deg,
                             float* __restrict__ dis, int N) {
    __shared__ int sm[256];
    int i = blockIdx.x * 256 + threadIdx.x;
    int c = (i < N) ? cnt[i] : 0;
    sm[threadIdx.x] = c; __syncthreads();
    for (int off = 1; off < 256; off <<= 1) {
        int u = (threadIdx.x >= off) ? sm[threadIdx.x - off] : 0;
        __syncthreads();
        sm[threadIdx.x] += u;
        __syncthreads();
    }
    if (i < N) {
        indptr[i] = bsum[blockIdx.x] + sm[threadIdx.x] - c;   // exclusive prefix
        dis[i] = 1.0f / sqrtf((float)(deg[i] + 1));           // +1 self-loop
    }
}

// ---------------- CSR fill: csr[indptr[col]+slot] = row ----------------
__global__ void fill_kernel(const int* __restrict__ ei, int E,
                            const int* __restrict__ indptr, int* __restrict__ cur,
                            int* __restrict__ csr) {
    int e = blockIdx.x * 256 + threadIdx.x;
    if (e >= E) return;
    int r = ei[e], c = ei[E + e];
    int pos = indptr[c] + atomicAdd(&cur[c], 1);
    csr[pos] = r;
}

// ---------------- GEMM (LDS-staged W): g[n][o] = bf16(dis[n]*(A@W^T + b)) ----------------
// Round-4 disease: acc=76 of 84 VGPR left nothing for load pipelining -> each of the
// 190 B-loads exposed ~250cyc L2 latency (MfmaUtil 2.6%, all pipes idle, 144us).
// Fix: per-K-step W panel (19456B, pre-arranged contiguous) double-buffered in LDS,
// reg-staged (issue-early / ds_write-late). ds_read_b128 fragment reads hit all 32
// banks evenly (dword l15*16+lhi*4 mod 32 covers 0..31 uniformly) -> no swizzle needed.
__global__ __launch_bounds__(256) void gemm_kernel(
    const unsigned short* __restrict__ A, const unsigned short* __restrict__ Ws,
    const float* __restrict__ bp, const float* __restrict__ dis,
    unsigned short* __restrict__ g, int N)
{
    __shared__ __align__(16) unsigned short lds[2][9728];   // 2 x 19456B
    const int t = threadIdx.x;
    const int lane = t & 63;
    const int wave = t >> 6;
    const int l15 = lane & 15, lhi = lane >> 4;
    const int rowBase = blockIdx.x * 64 + wave * 16;

    f32x4 acc[19];
    #pragma unroll
    for (int i = 0; i < 19; ++i) acc[i] = (f32x4){0.f,0.f,0.f,0.f};

    const unsigned short* Ap = A + (size_t)(rowBase + l15) * 320 + lhi * 8;
    const uint4* Wsrc = (const uint4*)Ws;        // 16B chunks; 1216 chunks per K-step

    uint4 st[5];
    // prologue: stage step 0
    {
        const uint4* s = Wsrc;
        #pragma unroll
        for (int r = 0; r < 4; ++r) st[r] = s[t + 256 * r];
        if (t < 192) st[4] = s[t + 1024];
        uint4* d = (uint4*)lds[0];
        #pragma unroll
        for (int r = 0; r < 4; ++r) d[t + 256 * r] = st[r];
        if (t < 192) d[t + 1024] = st[4];
    }
    __syncthreads();

    #pragma unroll 2
    for (int ks = 0; ks < 10; ++ks) {
        if (ks < 9) {                              // issue next-panel loads early
            const uint4* s = Wsrc + (ks + 1) * 1216;
            #pragma unroll
            for (int r = 0; r < 4; ++r) st[r] = s[t + 256 * r];
            if (t < 192) st[4] = s[t + 1024];
        }
        bf16x8 a = *(const bf16x8*)(Ap + ks * 32);
        const unsigned short* lb = lds[ks & 1] + l15 * 32 + lhi * 8;
        #pragma unroll
        for (int cf = 0; cf < 19; ++cf) {
            bf16x8 b = *(const bf16x8*)(lb + cf * 512);   // col cf*16+l15, k-off lhi*8
            acc[cf] = __builtin_amdgcn_mfma_f32_16x16x32_bf16(a, b, acc[cf], 0, 0, 0);
        }
        if (ks < 9) {
            __syncthreads();                       // all waves done reading buf[(ks+1)&1]
            uint4* d = (uint4*)lds[(ks + 1) & 1];
            #pragma unroll
            for (int r = 0; r < 4; ++r) d[t + 256 * r] = st[r];
            if (t < 192) d[t + 1024] = st[4];
            __syncthreads();                       // staged panel visible
        }
    }

    const int n0 = rowBase + lhi * 4;
    float dd[4];
    #pragma unroll
    for (int r = 0; r < 4; ++r) dd[r] = (n0 + r < N) ? dis[n0 + r] : 0.f;
    #pragma unroll
    for (int cf = 0; cf < 19; ++cf) {
        int o = cf * 16 + l15;
        if (o < 300) {
            float bo = bp[o];
            #pragma unroll
            for (int r = 0; r < 4; ++r)
                if (n0 + r < N) g[(size_t)(n0 + r) * 320 + o] = f2bf(dd[r] * (acc[cf][r] + bo));
        }
    }
}

// ---------------- propagate (bf16 g, pre-scaled by dis): out[i] = dis[i]*(g[i]+sum g[src]) ----------------
// Neighbor loop unrolled x4 with independent accumulator sets (MLP).
// MODE 0: f32 compact [N][300] to d_out. MODE 1: leaky_relu + bf16 padded [Mpad][320].
template<int MODE>
__global__ void prop_kernel(const unsigned short* __restrict__ g, const int* __restrict__ indptr,
                            const int* __restrict__ csr, const float* __restrict__ dis,
                            void* __restrict__ outp, int N, int Mpad) {
    int wave = threadIdx.x >> 6;
    int lane = threadIdx.x & 63;
    int n = blockIdx.x * 4 + wave;
    if (n >= (MODE ? Mpad : N)) return;
    float aL0[3] = {0.f,0.f,0.f}, aH0[3] = {0.f,0.f,0.f};
    float aL1[3] = {0.f,0.f,0.f}, aH1[3] = {0.f,0.f,0.f};
    float aL2[3] = {0.f,0.f,0.f}, aH2[3] = {0.f,0.f,0.f};
    float aL3[3] = {0.f,0.f,0.f}, aH3[3] = {0.f,0.f,0.f};
    if (n < N) {
        const unsigned* gn = (const unsigned*)(g + (size_t)n * 320);
        #pragma unroll
        for (int s = 0; s < 3; ++s) {
            int e = lane + 64 * s;                 // uint index; bf16 pair (2e, 2e+1)
            if (e < 150) { unsigned u = gn[e]; aL0[s] = bflo(u); aH0[s] = bfhi(u); }
        }
        int beg = indptr[n], end = indptr[n + 1];
        int j = beg;
        for (; j + 4 <= end; j += 4) {
            int s0 = csr[j], s1 = csr[j+1], s2 = csr[j+2], s3 = csr[j+3];
            const unsigned* g0 = (const unsigned*)(g + (size_t)s0 * 320);
            const unsigned* g1 = (const unsigned*)(g + (size_t)s1 * 320);
            const unsigned* g2 = (const unsigned*)(g + (size_t)s2 * 320);
            const unsigned* g3 = (const unsigned*)(g + (size_t)s3 * 320);
            #pragma unroll
            for (int s = 0; s < 3; ++s) {
                int e = lane + 64 * s;
                if (e < 150) {
                    unsigned u0 = g0[e], u1 = g1[e], u2 = g2[e], u3 = g3[e];
                    aL0[s] += bflo(u0); aH0[s] += bfhi(u0);
                    aL1[s] += bflo(u1); aH1[s] += bfhi(u1);
                    aL2[s] += bflo(u2); aH2[s] += bfhi(u2);
                    aL3[s] += bflo(u3); aH3[s] += bfhi(u3);
                }
            }
        }
        for (; j < end; ++j) {
            int src = csr[j];
            const unsigned* gs = (const unsigned*)(g + (size_t)src * 320);
            #pragma unroll
            for (int s = 0; s < 3; ++s) {
                int e = lane + 64 * s;
                if (e < 150) { unsigned u = gs[e]; aL0[s] += bflo(u); aH0[s] += bfhi(u); }
            }
        }
        float dn = dis[n];
        #pragma unroll
        for (int s = 0; s < 3; ++s) {
            aL0[s] = dn * ((aL0[s] + aL1[s]) + (aL2[s] + aL3[s]));
            aH0[s] = dn * ((aH0[s] + aH1[s]) + (aH2[s] + aH3[s]));
        }
    }
    if (MODE == 0) {
        float* out = (float*)outp + (size_t)n * 300;
        #pragma unroll
        for (int s = 0; s < 3; ++s) {
            int e = lane + 64 * s;
            if (e < 150) { float2 st = {aL0[s], aH0[s]}; *(float2*)(out + 2 * e) = st; }
        }
    } else {
        unsigned* h = (unsigned*)outp + (size_t)n * 160;
        #pragma unroll
        for (int s = 0; s < 3; ++s) {
            int e = lane + 64 * s;
            if (e < 150) {
                float vL = aL0[s]; vL = vL > 0.f ? vL : 0.01f * vL;
                float vH = aH0[s]; vH = vH > 0.f ? vH : 0.01f * vH;
                h[e] = pack2bf(vL, vH);
            } else if (e < 160) {
                h[e] = 0;                          // K-pad cols 300..319
            }
        }
    }
}

extern "C" void kernel_launch(void* const* d_in, const int* in_sizes, int n_in,
                              void* d_out, int out_size, void* d_ws, size_t ws_size,
                              hipStream_t stream) {
    const float* x  = (const float*)d_in[0];
    const int*   ei = (const int*)d_in[1];
    const float* W1 = (const float*)d_in[2];
    const float* b1 = (const float*)d_in[3];
    const float* W2 = (const float*)d_in[4];
    const float* b2 = (const float*)d_in[5];
    float* out = (float*)d_out;

    const int N = in_sizes[0] / 1200;     // 50000
    const int E = in_sizes[1] / 2;        // 250000
    const int Mpad = ((N + 127) / 128) * 128;   // 50048 (multiple of 64)
    const int NB = (N + 255) / 256;       // 196 scan tiles

    // ---- carve workspace (256B aligned) ----
    char* p = (char*)d_ws;
    auto carve = [&](size_t bytes) -> char* {
        char* r = p; p += (bytes + 255) & ~(size_t)255; return r;
    };
    unsigned short* xm   = (unsigned short*)carve((size_t)Mpad * 320 * 2);  // 32 MB
    unsigned short* g1   = (unsigned short*)carve((size_t)Mpad * 320 * 2);  // 32 MB
    unsigned short* hb   = (unsigned short*)carve((size_t)Mpad * 320 * 2);  // 32 MB
    unsigned short* g2   = (unsigned short*)carve((size_t)Mpad * 320 * 2);  // 32 MB
    float* dis           = (float*)carve((size_t)N * 4);
    int* deg             = (int*)carve((size_t)N * 4);
    int* cnt             = (int*)carve((size_t)N * 4);
    int* indptr          = (int*)carve((size_t)(N + 1) * 4);
    int* cur             = (int*)carve((size_t)N * 4);
    int* csr             = (int*)carve((size_t)E * 4);
    int* bsum            = (int*)carve(256 * 4);
    unsigned short* Ws1  = (unsigned short*)carve(304 * 320 * 2);   // staged [10][304][32]
    unsigned short* Ws2  = (unsigned short*)carve(304 * 320 * 2);
    float* bp1           = (float*)carve(304 * 4);
    float* bp2           = (float*)carve(304 * 4);

    setup_kernel <<<(304 * 320 + 255) / 256, 256, 0, stream>>>(W1, b1, W2, b2, Ws1, Ws2, bp1, bp2,
                                                               deg, cnt, cur, N);
    pool_kernel  <<<(Mpad * 40 + 255) / 256, 256, 0, stream>>>(x, xm, N, Mpad);
    degcnt_kernel<<<(E + 255) / 256, 256, 0, stream>>>(ei, E, deg, cnt);
    scanA_kernel <<<NB, 256, 0, stream>>>(cnt, bsum, N);
    scanB_kernel <<<1, 256, 0, stream>>>(bsum, NB, indptr, N);
    scanC_kernel <<<NB, 256, 0, stream>>>(cnt, bsum, indptr, deg, dis, N);
    fill_kernel  <<<(E + 255) / 256, 256, 0, stream>>>(ei, E, indptr, cur, csr);

    // layer 1: g1 = bf16(dis*(xm@W1^T + b1)); prop+leaky -> hb (bf16 padded)
    gemm_kernel  <<<Mpad / 64, 256, 0, stream>>>(xm, Ws1, bp1, dis, g1, N);
    prop_kernel<1><<<Mpad / 4, 256, 0, stream>>>(g1, indptr, csr, dis, hb, N, Mpad);
    // layer 2: g2 = bf16(dis*(hb@W2^T + b2)); final prop -> d_out (f32)
    gemm_kernel  <<<Mpad / 64, 256, 0, stream>>>(hb, Ws2, bp2, dis, g2, N);
    prop_kernel<0><<<(N + 3) / 4, 256, 0, stream>>>(g2, indptr, csr, dis, out, N, Mpad);
}

// Round 6
// 348.618 us; speedup vs baseline: 1.4799x; 1.0275x over previous
//
#include <hip/hip_runtime.h>

typedef __attribute__((ext_vector_type(8))) short bf16x8;
typedef __attribute__((ext_vector_type(4))) float f32x4;

__device__ __forceinline__ unsigned short f2bf(float f) {
    union { float f; unsigned u; } v; v.f = f;
    unsigned r = (v.u + 0x7FFFu + ((v.u >> 16) & 1u)) >> 16;   // round-to-nearest-even
    return (unsigned short)r;
}
__device__ __forceinline__ unsigned pack2bf(float a, float b) {
    return (unsigned)f2bf(a) | ((unsigned)f2bf(b) << 16);
}
__device__ __forceinline__ float bflo(unsigned u) { union { unsigned u; float f; } v; v.u = u << 16; return v.f; }
__device__ __forceinline__ float bfhi(unsigned u) { union { unsigned u; float f; } v; v.u = u & 0xffff0000u; return v.f; }

// ---------------- K0: mean-pool over T=4 + bf16 cast, padded [Mpad][320] ----------------
__global__ void pool_kernel(const float* __restrict__ x, unsigned short* __restrict__ xm,
                            int N, int Mpad) {
    int tid = blockIdx.x * 256 + threadIdx.x;
    if (tid >= Mpad * 40) return;
    int n = tid / 40, k8 = tid % 40;
    int k = k8 * 8;
    float v[8] = {0.f,0.f,0.f,0.f,0.f,0.f,0.f,0.f};
    if (n < N && k < 300) {
        const float* xp = x + (size_t)n * 1200 + k;
        #pragma unroll
        for (int t = 0; t < 4; ++t) {
            const float4 lo = *(const float4*)(xp + t * 300);
            v[0] += lo.x; v[1] += lo.y; v[2] += lo.z; v[3] += lo.w;
            if (k + 4 < 300) {   // k==296 tail: cols 300..303 stay zero
                const float4 hi = *(const float4*)(xp + t * 300 + 4);
                v[4] += hi.x; v[5] += hi.y; v[6] += hi.z; v[7] += hi.w;
            }
        }
    }
    union { unsigned short u[8]; bf16x8 vec; } p;
    #pragma unroll
    for (int j = 0; j < 8; ++j) p.u[j] = f2bf(v[j] * 0.25f);
    *(bf16x8*)(xm + (size_t)tid * 8) = p.vec;   // tid*8 == n*320 + k
}

// ---------------- setup: zero counters + weight prep ----------------
// W [300][300] f32 -> staged bf16 layout Ws[ks][col][kk]: ks=k/32 (10 steps), col<304, kk=k%32.
// Each K-step panel is a contiguous 19456B chunk, so GEMM staging is a linear 16B-chunk copy.
__global__ void setup_kernel(const float* __restrict__ W1, const float* __restrict__ b1,
                             const float* __restrict__ W2, const float* __restrict__ b2,
                             unsigned short* __restrict__ Ws1, unsigned short* __restrict__ Ws2,
                             float* __restrict__ bp1, float* __restrict__ bp2,
                             int* __restrict__ deg, int* __restrict__ cnt, int* __restrict__ cur, int N) {
    int tid = blockIdx.x * 256 + threadIdx.x;
    if (tid < N) { deg[tid] = 0; cnt[tid] = 0; cur[tid] = 0; }
    if (tid < 304 * 320) {
        int c = tid / 320, k = tid % 320;
        int ks = k / 32, kk = k % 32;
        int dst = ks * 9728 + c * 32 + kk;       // 9728 = 304*32 ushorts per K-step
        bool in = (c < 300) && (k < 300);
        Ws1[dst] = f2bf(in ? W1[c * 300 + k] : 0.f);
        Ws2[dst] = f2bf(in ? W2[c * 300 + k] : 0.f);
        if (tid < 304) { bp1[tid] = tid < 300 ? b1[tid] : 0.f; bp2[tid] = tid < 300 ? b2[tid] : 0.f; }
    }
}

// ---------------- degree (row/source) + in-degree counts (col/dest) ----------------
__global__ void degcnt_kernel(const int* __restrict__ ei, int E,
                              int* __restrict__ deg, int* __restrict__ cnt) {
    int e = blockIdx.x * 256 + threadIdx.x;
    if (e >= E) return;
    atomicAdd(&deg[ei[e]], 1);        // row
    atomicAdd(&cnt[ei[E + e]], 1);    // col
}

// ---------------- coalesced 3-phase scan: cnt -> indptr ----------------
__global__ void scanA_kernel(const int* __restrict__ cnt, int* __restrict__ bsum, int N) {
    __shared__ int sm[256];
    int i = blockIdx.x * 256 + threadIdx.x;
    sm[threadIdx.x] = (i < N) ? cnt[i] : 0;
    __syncthreads();
    for (int off = 128; off > 0; off >>= 1) {
        if (threadIdx.x < off) sm[threadIdx.x] += sm[threadIdx.x + off];
        __syncthreads();
    }
    if (threadIdx.x == 0) bsum[blockIdx.x] = sm[0];
}

__global__ void scanB_kernel(int* __restrict__ bsum, int nb, int* __restrict__ indptr, int N) {
    __shared__ int sm[256];
    int t = threadIdx.x;
    int v = (t < nb) ? bsum[t] : 0;
    sm[t] = v; __syncthreads();
    for (int off = 1; off < 256; off <<= 1) {
        int u = (t >= off) ? sm[t - off] : 0;
        __syncthreads();
        sm[t] += u;
        __syncthreads();
    }
    if (t < nb) bsum[t] = sm[t] - v;          // exclusive block offsets
    if (t == 255) indptr[N] = sm[255];        // total = E
}

__global__ void scanC_kernel(const int* __restrict__ cnt, const int* __restrict__ bsum,
                             int* __restrict__ indptr, const int* __restrict__ deg,
                             float* __restrict__ dis, int N) {
    __shared__ int sm[256];
    int i = blockIdx.x * 256 + threadIdx.x;
    int c = (i < N) ? cnt[i] : 0;
    sm[threadIdx.x] = c; __syncthreads();
    for (int off = 1; off < 256; off <<= 1) {
        int u = (threadIdx.x >= off) ? sm[threadIdx.x - off] : 0;
        __syncthreads();
        sm[threadIdx.x] += u;
        __syncthreads();
    }
    if (i < N) {
        indptr[i] = bsum[blockIdx.x] + sm[threadIdx.x] - c;   // exclusive prefix
        dis[i] = 1.0f / sqrtf((float)(deg[i] + 1));           // +1 self-loop
    }
}

// ---------------- CSR fill: csr[indptr[col]+slot] = row ----------------
__global__ void fill_kernel(const int* __restrict__ ei, int E,
                            const int* __restrict__ indptr, int* __restrict__ cur,
                            int* __restrict__ csr) {
    int e = blockIdx.x * 256 + threadIdx.x;
    if (e >= E) return;
    int r = ei[e], c = ei[E + e];
    int pos = indptr[c] + atomicAdd(&cur[c], 1);
    csr[pos] = r;
}

// ---------------- GEMM (LDS-staged W): g[n][o] = bf16(dis[n]*(A@W^T + b)) ----------------
// Per-K-step W panel (19456B, pre-arranged contiguous) double-buffered in LDS,
// reg-staged (issue-early / ds_write-late). ds_read_b128 fragment reads hit all 32
// banks evenly (dword l15*16+lhi*4 mod 32 covers 0..31 uniformly) -> no swizzle needed.
__global__ __launch_bounds__(256) void gemm_kernel(
    const unsigned short* __restrict__ A, const unsigned short* __restrict__ Ws,
    const float* __restrict__ bp, const float* __restrict__ dis,
    unsigned short* __restrict__ g, int N)
{
    __shared__ __align__(16) unsigned short lds[2][9728];   // 2 x 19456B
    const int t = threadIdx.x;
    const int lane = t & 63;
    const int wave = t >> 6;
    const int l15 = lane & 15, lhi = lane >> 4;
    const int rowBase = blockIdx.x * 64 + wave * 16;

    f32x4 acc[19];
    #pragma unroll
    for (int i = 0; i < 19; ++i) acc[i] = (f32x4){0.f,0.f,0.f,0.f};

    const unsigned short* Ap = A + (size_t)(rowBase + l15) * 320 + lhi * 8;
    const uint4* Wsrc = (const uint4*)Ws;        // 16B chunks; 1216 chunks per K-step

    uint4 st[5];
    // prologue: stage step 0
    {
        const uint4* s = Wsrc;
        #pragma unroll
        for (int r = 0; r < 4; ++r) st[r] = s[t + 256 * r];
        if (t < 192) st[4] = s[t + 1024];
        uint4* d = (uint4*)lds[0];
        #pragma unroll
        for (int r = 0; r < 4; ++r) d[t + 256 * r] = st[r];
        if (t < 192) d[t + 1024] = st[4];
    }
    __syncthreads();

    #pragma unroll 2
    for (int ks = 0; ks < 10; ++ks) {
        if (ks < 9) {                              // issue next-panel loads early
            const uint4* s = Wsrc + (ks + 1) * 1216;
            #pragma unroll
            for (int r = 0; r < 4; ++r) st[r] = s[t + 256 * r];
            if (t < 192) st[4] = s[t + 1024];
        }
        bf16x8 a = *(const bf16x8*)(Ap + ks * 32);
        const unsigned short* lb = lds[ks & 1] + l15 * 32 + lhi * 8;
        #pragma unroll
        for (int cf = 0; cf < 19; ++cf) {
            bf16x8 b = *(const bf16x8*)(lb + cf * 512);   // col cf*16+l15, k-off lhi*8
            acc[cf] = __builtin_amdgcn_mfma_f32_16x16x32_bf16(a, b, acc[cf], 0, 0, 0);
        }
        if (ks < 9) {
            __syncthreads();                       // all waves done reading buf[(ks+1)&1]
            uint4* d = (uint4*)lds[(ks + 1) & 1];
            #pragma unroll
            for (int r = 0; r < 4; ++r) d[t + 256 * r] = st[r];
            if (t < 192) d[t + 1024] = st[4];
            __syncthreads();                       // staged panel visible
        }
    }

    const int n0 = rowBase + lhi * 4;
    float dd[4];
    #pragma unroll
    for (int r = 0; r < 4; ++r) dd[r] = (n0 + r < N) ? dis[n0 + r] : 0.f;
    #pragma unroll
    for (int cf = 0; cf < 19; ++cf) {
        int o = cf * 16 + l15;
        if (o < 300) {
            float bo = bp[o];
            #pragma unroll
            for (int r = 0; r < 4; ++r)
                if (n0 + r < N) g[(size_t)(n0 + r) * 320 + o] = f2bf(dd[r] * (acc[cf][r] + bo));
        }
    }
}

// ---------------- propagate (bf16 g, pre-scaled by dis): out[i] = dis[i]*(g[i]+sum g[src]) ----------------
// One-issue row gather: padded row = 640B = 40 uint4; lanes 0..37 each read ONE uint4
// (vs round-5's 3 dword loads + 3 waitcnts per row). Lane 37's top 8B are pad-col poison,
// masked at write. x4 neighbor unroll keeps 4 independent uint4 loads in flight.
// MODE 0: f32 compact [N][300] to d_out. MODE 1: leaky_relu + bf16 padded [Mpad][320].
template<int MODE>
__global__ void prop_kernel(const unsigned short* __restrict__ g, const int* __restrict__ indptr,
                            const int* __restrict__ csr, const float* __restrict__ dis,
                            void* __restrict__ outp, int N, int Mpad) {
    int wave = threadIdx.x >> 6;
    int lane = threadIdx.x & 63;
    int n = blockIdx.x * 4 + wave;
    if (n >= (MODE ? Mpad : N)) return;
    const bool act = lane < 38;                    // 38*16B = 608B >= 600B of real cols
    float aL[4] = {0.f,0.f,0.f,0.f}, aH[4] = {0.f,0.f,0.f,0.f};
    if (n < N) {
        if (act) {
            uint4 u = *((const uint4*)(g + (size_t)n * 320) + lane);
            aL[0] = bflo(u.x); aH[0] = bfhi(u.x);
            aL[1] = bflo(u.y); aH[1] = bfhi(u.y);
            aL[2] = bflo(u.z); aH[2] = bfhi(u.z);
            aL[3] = bflo(u.w); aH[3] = bfhi(u.w);
        }
        int beg = indptr[n], end = indptr[n + 1];
        int j = beg;
        for (; j + 4 <= end; j += 4) {
            int s0 = csr[j], s1 = csr[j+1], s2 = csr[j+2], s3 = csr[j+3];
            const uint4* p0 = (const uint4*)(g + (size_t)s0 * 320) + lane;
            const uint4* p1 = (const uint4*)(g + (size_t)s1 * 320) + lane;
            const uint4* p2 = (const uint4*)(g + (size_t)s2 * 320) + lane;
            const uint4* p3 = (const uint4*)(g + (size_t)s3 * 320) + lane;
            if (act) {
                uint4 u0 = *p0, u1 = *p1, u2 = *p2, u3 = *p3;
                aL[0] += bflo(u0.x) + bflo(u1.x) + bflo(u2.x) + bflo(u3.x);
                aH[0] += bfhi(u0.x) + bfhi(u1.x) + bfhi(u2.x) + bfhi(u3.x);
                aL[1] += bflo(u0.y) + bflo(u1.y) + bflo(u2.y) + bflo(u3.y);
                aH[1] += bfhi(u0.y) + bfhi(u1.y) + bfhi(u2.y) + bfhi(u3.y);
                aL[2] += bflo(u0.z) + bflo(u1.z) + bflo(u2.z) + bflo(u3.z);
                aH[2] += bfhi(u0.z) + bfhi(u1.z) + bfhi(u2.z) + bfhi(u3.z);
                aL[3] += bflo(u0.w) + bflo(u1.w) + bflo(u2.w) + bflo(u3.w);
                aH[3] += bfhi(u0.w) + bfhi(u1.w) + bfhi(u2.w) + bfhi(u3.w);
            }
        }
        for (; j < end; ++j) {
            const uint4* ps = (const uint4*)(g + (size_t)csr[j] * 320) + lane;
            if (act) {
                uint4 u = *ps;
                aL[0] += bflo(u.x); aH[0] += bfhi(u.x);
                aL[1] += bflo(u.y); aH[1] += bfhi(u.y);
                aL[2] += bflo(u.z); aH[2] += bfhi(u.z);
                aL[3] += bflo(u.w); aH[3] += bfhi(u.w);
            }
        }
        float dn = dis[n];
        #pragma unroll
        for (int i = 0; i < 4; ++i) { aL[i] *= dn; aH[i] *= dn; }
    }
    if (MODE == 0) {
        // lane l covers f32 cols 8l..8l+7; lane 37 only 296..299 valid
        float* out = (float*)outp + (size_t)n * 300 + lane * 8;
        if (lane < 37) {
            float4 f0 = {aL[0], aH[0], aL[1], aH[1]};
            float4 f1 = {aL[2], aH[2], aL[3], aH[3]};
            *(float4*)out = f0;
            *(float4*)(out + 4) = f1;
        } else if (lane == 37) {
            float4 f0 = {aL[0], aH[0], aL[1], aH[1]};
            *(float4*)out = f0;
        }
    } else {
        uint4* h = (uint4*)((unsigned*)outp + (size_t)n * 160) + lane;
        if (lane < 40) {
            uint4 w = {0u, 0u, 0u, 0u};
            if (act) {
                float vL, vH;
                vL = aL[0]; vL = vL > 0.f ? vL : 0.01f * vL;
                vH = aH[0]; vH = vH > 0.f ? vH : 0.01f * vH;
                w.x = pack2bf(vL, vH);
                vL = aL[1]; vL = vL > 0.f ? vL : 0.01f * vL;
                vH = aH[1]; vH = vH > 0.f ? vH : 0.01f * vH;
                w.y = pack2bf(vL, vH);
                vL = aL[2]; vL = vL > 0.f ? vL : 0.01f * vL;
                vH = aH[2]; vH = vH > 0.f ? vH : 0.01f * vH;
                w.z = pack2bf(vL, vH);
                vL = aL[3]; vL = vL > 0.f ? vL : 0.01f * vL;
                vH = aH[3]; vH = vH > 0.f ? vH : 0.01f * vH;
                w.w = pack2bf(vL, vH);
                if (lane == 37) { w.z = 0u; w.w = 0u; }   // cols 300..303 = K-pad
            }
            *h = w;                                       // lanes 38,39 zero cols 304..319
        }
    }
}

extern "C" void kernel_launch(void* const* d_in, const int* in_sizes, int n_in,
                              void* d_out, int out_size, void* d_ws, size_t ws_size,
                              hipStream_t stream) {
    const float* x  = (const float*)d_in[0];
    const int*   ei = (const int*)d_in[1];
    const float* W1 = (const float*)d_in[2];
    const float* b1 = (const float*)d_in[3];
    const float* W2 = (const float*)d_in[4];
    const float* b2 = (const float*)d_in[5];
    float* out = (float*)d_out;

    const int N = in_sizes[0] / 1200;     // 50000
    const int E = in_sizes[1] / 2;        // 250000
    const int Mpad = ((N + 127) / 128) * 128;   // 50048 (multiple of 64)
    const int NB = (N + 255) / 256;       // 196 scan tiles

    // ---- carve workspace (256B aligned) ----
    char* p = (char*)d_ws;
    auto carve = [&](size_t bytes) -> char* {
        char* r = p; p += (bytes + 255) & ~(size_t)255; return r;
    };
    unsigned short* xm   = (unsigned short*)carve((size_t)Mpad * 320 * 2);  // 32 MB
    unsigned short* g1   = (unsigned short*)carve((size_t)Mpad * 320 * 2);  // 32 MB
    unsigned short* hb   = (unsigned short*)carve((size_t)Mpad * 320 * 2);  // 32 MB
    unsigned short* g2   = (unsigned short*)carve((size_t)Mpad * 320 * 2);  // 32 MB
    float* dis           = (float*)carve((size_t)N * 4);
    int* deg             = (int*)carve((size_t)N * 4);
    int* cnt             = (int*)carve((size_t)N * 4);
    int* indptr          = (int*)carve((size_t)(N + 1) * 4);
    int* cur             = (int*)carve((size_t)N * 4);
    int* csr             = (int*)carve((size_t)E * 4);
    int* bsum            = (int*)carve(256 * 4);
    unsigned short* Ws1  = (unsigned short*)carve(304 * 320 * 2);   // staged [10][304][32]
    unsigned short* Ws2  = (unsigned short*)carve(304 * 320 * 2);
    float* bp1           = (float*)carve(304 * 4);
    float* bp2           = (float*)carve(304 * 4);

    setup_kernel <<<(304 * 320 + 255) / 256, 256, 0, stream>>>(W1, b1, W2, b2, Ws1, Ws2, bp1, bp2,
                                                               deg, cnt, cur, N);
    pool_kernel  <<<(Mpad * 40 + 255) / 256, 256, 0, stream>>>(x, xm, N, Mpad);
    degcnt_kernel<<<(E + 255) / 256, 256, 0, stream>>>(ei, E, deg, cnt);
    scanA_kernel <<<NB, 256, 0, stream>>>(cnt, bsum, N);
    scanB_kernel <<<1, 256, 0, stream>>>(bsum, NB, indptr, N);
    scanC_kernel <<<NB, 256, 0, stream>>>(cnt, bsum, indptr, deg, dis, N);
    fill_kernel  <<<(E + 255) / 256, 256, 0, stream>>>(ei, E, indptr, cur, csr);

    // layer 1: g1 = bf16(dis*(xm@W1^T + b1)); prop+leaky -> hb (bf16 padded)
    gemm_kernel  <<<Mpad / 64, 256, 0, stream>>>(xm, Ws1, bp1, dis, g1, N);
    prop_kernel<1><<<Mpad / 4, 256, 0, stream>>>(g1, indptr, csr, dis, hb, N, Mpad);
    // layer 2: g2 = bf16(dis*(hb@W2^T + b2)); final prop -> d_out (f32)
    gemm_kernel  <<<Mpad / 64, 256, 0, stream>>>(hb, Ws2, bp2, dis, g2, N);
    prop_kernel<0><<<(N + 3) / 4, 256, 0, stream>>>(g2, indptr, csr, dis, out, N, Mpad);
}